// Round 1
// 4534.940 us; speedup vs baseline: 1.3691x; 1.3691x over previous
//
#include <hip/hip_runtime.h>
#include <cstddef>
#include <cstdint>

// Problem constants
constexpr int Bc  = 4;
constexpr int Sc  = 512;
constexpr int Dc  = 1024;
constexpr int Hc  = 16;
constexpr int DHc = 64;
constexpr int DFFc = 4096;
constexpr int Lc  = 6;
constexpr int Mrows = Bc * Sc;          // 2048 token rows
constexpr float LN_EPS = 1e-5f;
constexpr float INV_SQRT_DK = 0.125f;   // 1/sqrt(64)
constexpr float NEG_BIG = -1e30f;
constexpr int QS = 3 * Dc;              // fused QKV row stride = 3072

typedef __attribute__((ext_vector_type(8))) short bf16x8;
typedef __attribute__((ext_vector_type(4))) float f32x4;
typedef __attribute__((ext_vector_type(8))) unsigned short us8;

// ---------------------------------------------------------------------------
// bf16 split helpers: x = hi + lo + O(2^-18 |x|)
// ---------------------------------------------------------------------------
__device__ __forceinline__ unsigned short bf_rne(float x) {
  unsigned u = __float_as_uint(x);
  return (unsigned short)((u + 0x7fffu + ((u >> 16) & 1u)) >> 16);
}
__device__ __forceinline__ unsigned short bf_hi(float x, float& rem) {
  unsigned u = __float_as_uint(x);
  unsigned r = (u + 0x7fffu + ((u >> 16) & 1u)) >> 16;
  rem = x - __uint_as_float(r << 16);
  return (unsigned short)r;
}

// global -> LDS direct copy, 16B per lane; LDS dest is wave-uniform base.
#define GLD16(g, l)                                                        \
  __builtin_amdgcn_global_load_lds(                                        \
      (__attribute__((address_space(1))) void*)(void*)(g),                 \
      (__attribute__((address_space(3))) void*)(l), 16, 0, 0)

// ---------------------------------------------------------------------------
// Embedding: x[row] = word_emb[tok] + pos_table[tok]; also emit bf16 hi/lo.
// grid = 2048 blocks, 256 threads (float4 each)
// ---------------------------------------------------------------------------
__global__ __launch_bounds__(256) void embed_kernel(
    const int* __restrict__ enc, const float* __restrict__ we,
    const float* __restrict__ pt, float* __restrict__ x,
    short* __restrict__ xhi, short* __restrict__ xlo) {
  const int row = blockIdx.x;
  const int tok = enc[row];
  const int i = threadIdx.x;
  float4 a = ((const float4*)(we + (size_t)tok * Dc))[i];
  float4 b = ((const float4*)(pt + (size_t)tok * Dc))[i];
  float4 s = make_float4(a.x + b.x, a.y + b.y, a.z + b.z, a.w + b.w);
  ((float4*)(x + (size_t)row * Dc))[i] = s;
  ushort4 hh, ll; float rem;
  hh.x = bf_hi(s.x, rem); ll.x = bf_rne(rem);
  hh.y = bf_hi(s.y, rem); ll.y = bf_rne(rem);
  hh.z = bf_hi(s.z, rem); ll.z = bf_rne(rem);
  hh.w = bf_hi(s.w, rem); ll.w = bf_rne(rem);
  *(ushort4*)(xhi + (size_t)row * Dc + i * 4) = hh;
  *(ushort4*)(xlo + (size_t)row * Dc + i * 4) = ll;
}

// ---------------------------------------------------------------------------
// Weight convert: fp32 W[K][N] -> bf16 hi/lo in GEMM-tiled layout:
//   tile (nt,kt) at ((ntoff+nt)*k32tot + kt)*4096, stored [128 n][32 k].
// grid = (ncols/128, K/32), 256 threads.
// ---------------------------------------------------------------------------
__global__ __launch_bounds__(256) void convw_kernel(
    const float* __restrict__ W, int ldw, short* __restrict__ hi,
    short* __restrict__ lo, int k32tot, int ntoff) {
  __shared__ float t[32][132];
  const int nt = blockIdx.x;
  const int kt = blockIdx.y;
  const int tid = threadIdx.x;
  {
    const int r = tid >> 3;           // 0..31
    const int c = (tid & 7) * 16;     // 0..112
    const float4* s4 = (const float4*)(W + (size_t)(kt * 32 + r) * ldw + nt * 128 + c);
    float4 v0 = s4[0], v1 = s4[1], v2 = s4[2], v3 = s4[3];
    *(float4*)&t[r][c + 0]  = v0;
    *(float4*)&t[r][c + 4]  = v1;
    *(float4*)&t[r][c + 8]  = v2;
    *(float4*)&t[r][c + 12] = v3;
  }
  __syncthreads();
  const int nin = tid >> 1;
  const int k0 = (tid & 1) * 16;
  const size_t base = ((size_t)(ntoff + nt) * k32tot + kt) * 4096 + nin * 32 + k0;
  us8 h0, h1, l0, l1;
#pragma unroll
  for (int i = 0; i < 8; ++i) {
    float rem;
    h0[i] = bf_hi(t[k0 + i][nin], rem);     l0[i] = bf_rne(rem);
  }
#pragma unroll
  for (int i = 0; i < 8; ++i) {
    float rem;
    h1[i] = bf_hi(t[k0 + 8 + i][nin], rem); l1[i] = bf_rne(rem);
  }
  *(us8*)(hi + base) = h0;
  *(us8*)(hi + base + 8) = h1;
  *(us8*)(lo + base) = l0;
  *(us8*)(lo + base + 8) = l1;
}

// concat bq|bk|bv -> fused bias[3072]
__global__ __launch_bounds__(256) void concat3_kernel(
    const float* __restrict__ a, const float* __restrict__ b,
    const float* __restrict__ c, float* __restrict__ o) {
  const int i = blockIdx.x * 256 + threadIdx.x;
  o[i] = (i < 1024) ? a[i] : (i < 2048 ? b[i - 1024] : c[i - 2048]);
}

// ---------------------------------------------------------------------------
// bf16x3-split MFMA GEMM.  C[M,N] = (Ahi+Alo)@(Bhi+Blo) approx over K'=3K:
//   sections: (Ahi,Bhi), (Alo,Bhi), (Ahi,Blo).
// A: [M][K] bf16 row-major. B: pre-tiled [ntile][K/32][128n][32k] bf16.
// BM x 128 tile, BK=32, 256 threads = 4 waves (2m x 2n), wave = (BM/2) x 64.
// Double-buffered LDS, global_load_lds width-16 staging (m97 structure).
// ---------------------------------------------------------------------------
template <int BM, int K, int N, bool RELU, bool RES, bool OUTS>
__global__ __launch_bounds__(256) void mgemm(
    const short* __restrict__ Ahi, const short* __restrict__ Alo,
    const short* __restrict__ Bhi, const short* __restrict__ Blo,
    const float* __restrict__ bias, const float* __restrict__ R,
    float* __restrict__ C, short* __restrict__ Chi, short* __restrict__ Clo) {
  constexpr int K32 = K / 32;
  constexpr int NT = 3 * K32;
  constexpr int MR = BM / 32;                 // frag rows per wave
  constexpr int AISS = (BM * 64) / 4096;      // A-tile 16B issues per thread

  __shared__ __align__(16) short As[2][BM * 32];
  __shared__ __align__(16) short Bs[2][128 * 32];

  const int tid = threadIdx.x;
  const int lane = tid & 63;
  const int wid = tid >> 6;
  const int wr = wid >> 1;
  const int wc = wid & 1;
  const int m0 = blockIdx.y * BM;
  const int n0 = blockIdx.x * 128;

  const int ar = tid >> 2;            // A staging row (0..63)
  const int akb = (tid & 3) * 16;     // byte within 64B row

  f32x4 zero = {0.f, 0.f, 0.f, 0.f};
  f32x4 acc[MR][4];
#pragma unroll
  for (int m = 0; m < MR; ++m)
#pragma unroll
    for (int n = 0; n < 4; ++n) acc[m][n] = zero;

  auto stage = [&](int t, int cb) {
    const int s = t / K32;            // constexpr-pow2 divide -> shift
    const int kt = t - s * K32;
    const short* Ap = (s == 1) ? Alo : Ahi;
    const short* Bp = (s == 2) ? Blo : Bhi;
    {
      char* src = (char*)Ap + (((size_t)(m0 + ar) * K + (size_t)kt * 32) << 1) + akb;
      char* dst = (char*)&As[cb][0] + wid * 1024;
      GLD16(src, dst);
      if constexpr (AISS == 2) GLD16(src + ((size_t)(64 * K) << 1), dst + 4096);
    }
    {
      char* src = (char*)Bp + (((size_t)blockIdx.x * K32 + kt) << 13) + tid * 16;
      char* dst = (char*)&Bs[cb][0] + wid * 1024;
      GLD16(src, dst);
      GLD16(src + 4096, dst + 4096);
    }
  };

  stage(0, 0);
  __syncthreads();   // compiler drains vmcnt(0) before barrier -> tile 0 ready

  const int l16 = lane & 15;
  const int g8 = (lane >> 4) * 8;

  for (int t = 0; t < NT; ++t) {
    const int cb = t & 1;
    if (t + 1 < NT) stage(t + 1, cb ^ 1);
    const short* as = &As[cb][(wr * (BM / 2) + l16) * 32 + g8];
    const short* bs = &Bs[cb][(wc * 64 + l16) * 32 + g8];
    bf16x8 af[MR], bfv[4];
#pragma unroll
    for (int m = 0; m < MR; ++m) af[m] = *(const bf16x8*)(as + m * 512);
#pragma unroll
    for (int n = 0; n < 4; ++n) bfv[n] = *(const bf16x8*)(bs + n * 512);
#pragma unroll
    for (int m = 0; m < MR; ++m)
#pragma unroll
      for (int n = 0; n < 4; ++n)
        acc[m][n] = __builtin_amdgcn_mfma_f32_16x16x32_bf16(af[m], bfv[n],
                                                            acc[m][n], 0, 0, 0);
    __syncthreads();
  }

  // Epilogue. C/D layout: col = lane&15, row = (lane>>4)*4 + reg.
  const int rg = (lane >> 4) * 4;
#pragma unroll
  for (int m = 0; m < MR; ++m) {
    const int rbase = m0 + wr * (BM / 2) + m * 16 + rg;
#pragma unroll
    for (int n = 0; n < 4; ++n) {
      const int col = n0 + wc * 64 + n * 16 + l16;
      const float bv = bias[col];
#pragma unroll
      for (int j = 0; j < 4; ++j) {
        const size_t idx = (size_t)(rbase + j) * N + col;
        float v = acc[m][n][j] + bv;
        if constexpr (RES) v += R[idx];
        if constexpr (RELU) v = fmaxf(v, 0.f);
        if constexpr (OUTS) {
          float rem;
          Chi[idx] = (short)bf_hi(v, rem);
          Clo[idx] = (short)bf_rne(rem);
        } else {
          C[idx] = v;
        }
      }
    }
  }
}

// ---------------------------------------------------------------------------
// LayerNorm over last dim (1024); optional fused bf16 hi/lo split output.
// ---------------------------------------------------------------------------
template <bool SPLIT>
__global__ __launch_bounds__(256) void ln_kernel(const float* __restrict__ in,
                                                 float* __restrict__ out,
                                                 short* __restrict__ hi,
                                                 short* __restrict__ lo) {
  const int row = blockIdx.x;
  const int t = threadIdx.x;
  float4 v = ((const float4*)(in + (size_t)row * Dc))[t];
  float s = v.x + v.y + v.z + v.w;
  float s2 = v.x * v.x + v.y * v.y + v.z * v.z + v.w * v.w;
#pragma unroll
  for (int off = 32; off; off >>= 1) {
    s += __shfl_down(s, off);
    s2 += __shfl_down(s2, off);
  }
  __shared__ float red[2][4];
  const int wid = t / 64;
  if ((t & 63) == 0) { red[0][wid] = s; red[1][wid] = s2; }
  __syncthreads();
  s = red[0][0] + red[0][1] + red[0][2] + red[0][3];
  s2 = red[1][0] + red[1][1] + red[1][2] + red[1][3];
  const float mean = s * (1.f / Dc);
  const float var = s2 * (1.f / Dc) - mean * mean;
  const float inv = rsqrtf(var + LN_EPS);
  float4 o = make_float4((v.x - mean) * inv, (v.y - mean) * inv,
                         (v.z - mean) * inv, (v.w - mean) * inv);
  ((float4*)(out + (size_t)row * Dc))[t] = o;
  if constexpr (SPLIT) {
    ushort4 hh, ll; float rem;
    hh.x = bf_hi(o.x, rem); ll.x = bf_rne(rem);
    hh.y = bf_hi(o.y, rem); ll.y = bf_rne(rem);
    hh.z = bf_hi(o.z, rem); ll.z = bf_rne(rem);
    hh.w = bf_hi(o.w, rem); ll.w = bf_rne(rem);
    *(ushort4*)(hi + (size_t)row * Dc + t * 4) = hh;
    *(ushort4*)(lo + (size_t)row * Dc + t * 4) = ll;
  }
}

// ---------------------------------------------------------------------------
// Fused attention for one (b, h, 16-row tile). Reads fused QKV (stride 3072),
// writes attn probs to corrs and AV directly as bf16 hi/lo split.
// grid = (S/16, H, B), 256 threads.
// ---------------------------------------------------------------------------
__global__ __launch_bounds__(256) void attn_kernel(
    const float* __restrict__ qkv, const int* __restrict__ enc,
    float* __restrict__ attn_out, short* __restrict__ avhi,
    short* __restrict__ avlo) {
  constexpr int AR = 16;
  const int rt = blockIdx.x;
  const int h = blockIdx.y;
  const int b = blockIdx.z;
  const int r0 = rt * AR;
  const int t = threadIdx.x;

  __shared__ float qs[AR][68];
  __shared__ float kt[DHc][68];
  __shared__ float sc[AR][516];

  const float* q = qkv;
  const float* k = qkv + Dc;
  const float* v = qkv + 2 * Dc;

  {
    const int r = t / 16;
    const int c4 = (t % 16) * 4;
    float4 qv = *(const float4*)(q + (size_t)(b * Sc + r0 + r) * QS + h * DHc + c4);
    *(float4*)&qs[r][c4] = qv;
  }

  const int r = t / 16;
  const int j0 = (t % 16) * 4;

  for (int jt = 0; jt < Sc / 64; ++jt) {
    __syncthreads();
    {
      const int j = t / 4;
      const int d0 = (t % 4) * 16;
      const float* krow = k + (size_t)(b * Sc + jt * 64 + j) * QS + h * DHc + d0;
#pragma unroll
      for (int ii = 0; ii < 4; ++ii) {
        float4 kv = ((const float4*)krow)[ii];
        kt[d0 + ii * 4 + 0][j] = kv.x;
        kt[d0 + ii * 4 + 1][j] = kv.y;
        kt[d0 + ii * 4 + 2][j] = kv.z;
        kt[d0 + ii * 4 + 3][j] = kv.w;
      }
    }
    __syncthreads();
    float c0 = 0.f, c1 = 0.f, c2 = 0.f, c3 = 0.f;
#pragma unroll
    for (int d = 0; d < DHc; ++d) {
      const float qd = qs[r][d];
      float4 kv = *(const float4*)&kt[d][j0];
      c0 += qd * kv.x; c1 += qd * kv.y; c2 += qd * kv.z; c3 += qd * kv.w;
    }
    sc[r][jt * 64 + j0 + 0] = c0 * INV_SQRT_DK;
    sc[r][jt * 64 + j0 + 1] = c1 * INV_SQRT_DK;
    sc[r][jt * 64 + j0 + 2] = c2 * INV_SQRT_DK;
    sc[r][jt * 64 + j0 + 3] = c3 * INV_SQRT_DK;
  }
  __syncthreads();

  const int lane16 = t % 16;
  float mx = NEG_BIG;
#pragma unroll
  for (int it = 0; it < 32; ++it) {
    const int j = lane16 + it * 16;
    float sv = sc[r][j];
    if (enc[b * Sc + j] == 0) sv = NEG_BIG;
    sc[r][j] = sv;
    mx = fmaxf(mx, sv);
  }
#pragma unroll
  for (int off = 8; off; off >>= 1) mx = fmaxf(mx, __shfl_xor(mx, off));
  float sum = 0.f;
#pragma unroll
  for (int it = 0; it < 32; ++it) {
    const int j = lane16 + it * 16;
    float e = __expf(sc[r][j] - mx);
    sc[r][j] = e;
    sum += e;
  }
#pragma unroll
  for (int off = 8; off; off >>= 1) sum += __shfl_xor(sum, off);
  const float inv = 1.f / sum;
  float* arow = attn_out + (((size_t)b * Hc + h) * Sc + (r0 + r)) * Sc;
#pragma unroll
  for (int it = 0; it < 32; ++it) {
    const int j = lane16 + it * 16;
    const float a = sc[r][j] * inv;
    sc[r][j] = a;
    arow[j] = a;
  }

  // --- AV = attn @ v ---
  const int d0 = (t % 16) * 4;
  float av0 = 0.f, av1 = 0.f, av2 = 0.f, av3 = 0.f;
  for (int jt = 0; jt < Sc / 64; ++jt) {
    __syncthreads();
    {
      const int j = t / 4;
      const int c0 = (t % 4) * 16;
      const float* vrow = v + (size_t)(b * Sc + jt * 64 + j) * QS + h * DHc + c0;
#pragma unroll
      for (int ii = 0; ii < 4; ++ii) {
        float4 vv = ((const float4*)vrow)[ii];
        *(float4*)&kt[j][c0 + ii * 4] = vv;
      }
    }
    __syncthreads();
#pragma unroll
    for (int j = 0; j < 64; ++j) {
      const float a = sc[r][jt * 64 + j];
      float4 vv = *(const float4*)&kt[j][d0];
      av0 += a * vv.x; av1 += a * vv.y; av2 += a * vv.z; av3 += a * vv.w;
    }
  }
  const size_t orow = (size_t)(b * Sc + r0 + r) * Dc + h * DHc + d0;
  ushort4 hh, ll; float rem;
  hh.x = bf_hi(av0, rem); ll.x = bf_rne(rem);
  hh.y = bf_hi(av1, rem); ll.y = bf_rne(rem);
  hh.z = bf_hi(av2, rem); ll.z = bf_rne(rem);
  hh.w = bf_hi(av3, rem); ll.w = bf_rne(rem);
  *(ushort4*)(avhi + orow) = hh;
  *(ushort4*)(avlo + orow) = ll;
}

// ---------------------------------------------------------------------------
// Launch
// ---------------------------------------------------------------------------
extern "C" void kernel_launch(void* const* d_in, const int* in_sizes, int n_in,
                              void* d_out, int out_size, void* d_ws,
                              size_t ws_size, hipStream_t stream) {
  const int* enc = (const int*)d_in[0];
  const float* we = (const float*)d_in[1];
  const float* pt = (const float*)d_in[2];
  const float* Wq = (const float*)d_in[3];
  const float* bq = (const float*)d_in[4];
  const float* Wk = (const float*)d_in[5];
  const float* bk = (const float*)d_in[6];
  const float* Wv = (const float*)d_in[7];
  const float* bv = (const float*)d_in[8];
  const float* Wo = (const float*)d_in[9];
  const float* bo = (const float*)d_in[10];
  const float* W1 = (const float*)d_in[11];
  const float* b1 = (const float*)d_in[12];
  const float* W2 = (const float*)d_in[13];
  const float* b2 = (const float*)d_in[14];

  float* out = (float*)d_out;
  float* corrs = out + (size_t)Mrows * Dc;

  constexpr size_t MEG = 1024 * 1024;  // floats
  float* ws = (float*)d_ws;
  // fp32 buffers
  float* X   = ws;                 // [0, 2M)   : residual / layer input
  float* QKVb= ws + 2 * MEG;       // [2M, 8M)  : fused QKV [2048][3072]
  float* T   = QKVb;               //   reused after attn
  float* X1  = QKVb + 2 * MEG;
  float* T2  = QKVb + 4 * MEG;
  // bf16 split buffers (shorts)
  short* Xhi = (short*)(ws + 8 * MEG);    // also X1 split (non-overlapping life)
  short* Xlo = (short*)(ws + 9 * MEG);
  short* AVhi= (short*)(ws + 10 * MEG);   // dead before FF split is written
  short* AVlo= (short*)(ws + 11 * MEG);
  short* FFhi= (short*)(ws + 10 * MEG);   // [10M,14M)
  short* FFlo= (short*)(ws + 14 * MEG);   // [14M,18M)
  short* Whi = (short*)(ws + 18 * MEG);   // [18M,20M) : 4M shorts
  short* Wlo = (short*)(ws + 20 * MEG);   // [20M,22M)
  float* b3  = ws + 22 * MEG;             // fused qkv bias [3072]
  // total ~88 MB

  const dim3 blk(256);
  embed_kernel<<<Mrows, blk, 0, stream>>>(enc, we, pt, X, Xhi, Xlo);

  for (int l = 0; l < Lc; ++l) {
    const float* wq = Wq + (size_t)l * Dc * Dc;
    const float* wk = Wk + (size_t)l * Dc * Dc;
    const float* wv = Wv + (size_t)l * Dc * Dc;
    const float* wo = Wo + (size_t)l * Dc * Dc;
    const float* w1 = W1 + (size_t)l * Dc * DFFc;
    const float* w2 = W2 + (size_t)l * DFFc * Dc;
    const float* lbq = bq + (size_t)l * Dc;
    const float* lbk = bk + (size_t)l * Dc;
    const float* lbv = bv + (size_t)l * Dc;
    const float* lbo = bo + (size_t)l * Dc;
    const float* lb1 = b1 + (size_t)l * DFFc;
    const float* lb2 = b2 + (size_t)l * Dc;
    float* lcorr = corrs + (size_t)l * Bc * Hc * Sc * Sc;

    // QKV fused: weights -> tiled bf16 split, then one MFMA GEMM [2048][3072]
    convw_kernel<<<dim3(8, 32), blk, 0, stream>>>(wq, Dc, Whi, Wlo, 32, 0);
    convw_kernel<<<dim3(8, 32), blk, 0, stream>>>(wk, Dc, Whi, Wlo, 32, 8);
    convw_kernel<<<dim3(8, 32), blk, 0, stream>>>(wv, Dc, Whi, Wlo, 32, 16);
    concat3_kernel<<<12, blk, 0, stream>>>(lbq, lbk, lbv, b3);
    mgemm<64, 1024, 3072, false, false, false><<<dim3(24, 32), blk, 0, stream>>>(
        Xhi, Xlo, Whi, Wlo, b3, nullptr, QKVb, nullptr, nullptr);

    attn_kernel<<<dim3(Sc / 16, Hc, Bc), blk, 0, stream>>>(QKVb, enc, lcorr,
                                                           AVhi, AVlo);

    // T = X + AV@Wo + bo
    convw_kernel<<<dim3(8, 32), blk, 0, stream>>>(wo, Dc, Whi, Wlo, 32, 0);
    mgemm<64, 1024, 1024, false, true, false><<<dim3(8, 32), blk, 0, stream>>>(
        AVhi, AVlo, Whi, Wlo, lbo, X, T, nullptr, nullptr);
    // X1 = LN(T), fused split for FF1's A operand
    ln_kernel<true><<<Mrows, blk, 0, stream>>>(T, X1, Xhi, Xlo);

    // FF = relu(X1@W1 + b1), epilogue writes split bf16 directly
    convw_kernel<<<dim3(32, 32), blk, 0, stream>>>(w1, DFFc, Whi, Wlo, 32, 0);
    mgemm<128, 1024, 4096, true, false, true><<<dim3(32, 16), blk, 0, stream>>>(
        Xhi, Xlo, Whi, Wlo, lb1, nullptr, nullptr, FFhi, FFlo);

    // T2 = X1 + FF@W2 + b2
    convw_kernel<<<dim3(8, 128), blk, 0, stream>>>(w2, Dc, Whi, Wlo, 128, 0);
    mgemm<64, 4096, 1024, false, true, false><<<dim3(8, 32), blk, 0, stream>>>(
        FFhi, FFlo, Whi, Wlo, lb2, X1, T2, nullptr, nullptr);

    if (l == Lc - 1)
      ln_kernel<false><<<Mrows, blk, 0, stream>>>(T2, out, nullptr, nullptr);
    else
      ln_kernel<true><<<Mrows, blk, 0, stream>>>(T2, X, Xhi, Xlo);
  }
}